// Round 5
// baseline (253.054 us; speedup 1.0000x reference)
//
#include <hip/hip_runtime.h>
#include <hip/hip_bf16.h>
#include <float.h>

// N=1024, M=1024, D=512, fp32.
// tanh(q+k) = 1 - 2/(1+exp2(CS*(q+k))), CS=2*log2(e), exp2 factorized:
// eqT[d][n]=exp2(CS*qp)^T, ek[m][d]=exp2(CS*kp).
// Score s[n,m] = -2*sum_d Ww[d]*rcp(1+eq*ek) (row-const dropped, softmax
// shift-invariant). |s|<=2*sum|Ww|~36 -> exp never overflows -> NO max pass.
// Score writes PT[m][n] = mask ? exp(s) : 0 (coalesced). rsum kernel makes
// inv rowsums; ctx computes out = (PT^T @ vp) * inv directly.
// ws (floats): eqT[512K] ek[512K] vp[512K] PT[1M] = 10.49 MB (confirmed safe).
// rinv[1024] reuses eqT space (dead after score).

#define NROWS 1024
#define DDIM  512
#define MDIM  1024

typedef float v2f __attribute__((ext_vector_type(2)));

__device__ __forceinline__ void load_lds16(const float* g, float* l) {
    __builtin_amdgcn_global_load_lds(
        (const __attribute__((address_space(1))) void*)g,
        (__attribute__((address_space(3))) void*)l, 16, 0, 0);
}

// ---------------- Fused projection GEMMs (A^T-B form) ------------------------
// out[R][C] = sum_k A[r][k]*B[c][k] (+bias, optional exp2*CS).
// z=0: eqT[d][n]: A=Wq, B=q, bias on R-row (d), exp2.
// z=1: ek[m][d]:  A=k,  B=Wk, bias on C-col (d), exp2.
// z=2: vp[m][d]:  A=v,  B=Wv, bias on C-col (d).
// LDS tiles k-major [k][r] with 16B-block XOR swizzle:
//   off(k, r) = k*64 + ((r>>2)^(k>>2 & 15))*4 + (r&3)
// -> coalesced global reads, conflict-free transposed stores AND b128 reads.
__global__ __launch_bounds__(256) void proj_gemm(
    const float* __restrict__ q, const float* __restrict__ kk_,
    const float* __restrict__ v,
    const float* __restrict__ Wq, const float* __restrict__ bq,
    const float* __restrict__ Wk, const float* __restrict__ bk,
    const float* __restrict__ Wv, const float* __restrict__ bv,
    float* __restrict__ eqT, float* __restrict__ ek, float* __restrict__ vp,
    float CS)
{
    __shared__ __align__(16) float As[64 * 64];
    __shared__ __align__(16) float Bs[64 * 64];

    const float* A; const float* B; const float* bias; float* out;
    int R, C, expo, biasRow;
    if (blockIdx.z == 0)      { A = Wq;  B = q;  bias = bq; out = eqT; R = 512;  C = 1024; expo = 1; biasRow = 1; }
    else if (blockIdx.z == 1) { A = kk_; B = Wk; bias = bk; out = ek;  R = 1024; C = 512;  expo = 1; biasRow = 0; }
    else                      { A = v;   B = Wv; bias = bv; out = vp;  R = 1024; C = 512;  expo = 0; biasRow = 0; }

    const int t  = threadIdx.x;
    const int tx = t & 15;            // C-frag group
    const int ty = t >> 4;            // R-frag group
    const int i0 = blockIdx.y * 64;   // R
    const int j0 = blockIdx.x * 64;   // C
    if (i0 >= R || j0 >= C) return;

    float acc[4][4] = {};

    for (int k0 = 0; k0 < DDIM; k0 += 64) {
        __syncthreads();
#pragma unroll
        for (int p = 0; p < 4; ++p) {
            int idx = t + p * 256;
            int r = idx >> 4, c4 = idx & 15;            // lanes sweep k: coalesced
            float4 av = *(const float4*)&A[(size_t)(i0 + r) * DDIM + k0 + c4 * 4];
            float4 bf = *(const float4*)&B[(size_t)(j0 + r) * DDIM + k0 + c4 * 4];
            int base = (c4 * 4) * 64 + (((r >> 2) ^ c4) << 2) + (r & 3);
            As[base]       = av.x;  As[base + 64]  = av.y;
            As[base + 128] = av.z;  As[base + 192] = av.w;
            Bs[base]       = bf.x;  Bs[base + 64]  = bf.y;
            Bs[base + 128] = bf.z;  Bs[base + 192] = bf.w;
        }
        __syncthreads();
#pragma unroll
        for (int kg = 0; kg < 16; ++kg) {
            const int ao = ((ty ^ kg) << 2);
            const int bo = ((tx ^ kg) << 2);
#pragma unroll
            for (int kq = 0; kq < 4; ++kq) {
                int kk = kg * 4 + kq;
                float4 a = *(const float4*)&As[kk * 64 + ao];
                float4 b = *(const float4*)&Bs[kk * 64 + bo];
                float av4[4] = {a.x, a.y, a.z, a.w};
                float bv4[4] = {b.x, b.y, b.z, b.w};
#pragma unroll
                for (int i = 0; i < 4; ++i)
#pragma unroll
                    for (int j = 0; j < 4; ++j)
                        acc[i][j] = fmaf(av4[i], bv4[j], acc[i][j]);
            }
        }
    }

#pragma unroll
    for (int i = 0; i < 4; ++i) {
        int row = i0 + ty * 4 + i;
        float4 o;
        float ov[4];
#pragma unroll
        for (int j = 0; j < 4; ++j) {
            float bval = biasRow ? bias[row] : bias[j0 + tx * 4 + j];
            float val = acc[i][j] + bval;
            ov[j] = expo ? __builtin_amdgcn_exp2f(val * CS) : val;
        }
        o.x = ov[0]; o.y = ov[1]; o.z = ov[2]; o.w = ov[3];
        *(float4*)&out[(size_t)row * C + j0 + tx * 4] = o;
    }
}

// ---------------- Score kernel ----------------------------------------------
// PT[m][n] = mask[n][m] ? exp(-2*sum_d Ww[d]*rcp(1+eqT[d][n]*ek[m][d])) : 0
// Block: 4 waves; wave w owns 2 m rows; lane owns 4 n.
// eqT chunk [32 d][256 n] via global_load_lds width=16 (1 KB rows).
#define DCH 32
__global__ __launch_bounds__(256) void score_kernel(const float* __restrict__ eqT,
                                                    const float* __restrict__ ek,
                                                    const float* __restrict__ Ww,
                                                    const int* __restrict__ mask,
                                                    float* __restrict__ PT)
{
    __shared__ __align__(16) float ks[DCH * 256];   // 32 KB
    __shared__ float es[8 * DCH];
    __shared__ float wws[DCH];

    const int t    = threadIdx.x;
    const int lane = t & 63;
    const int w    = t >> 6;
    const int n0   = blockIdx.x * 256;
    const int m0   = blockIdx.y * 8;

    v2f acc01[2] = {}, acc23[2] = {};
    const v2f one2 = {1.f, 1.f};

    for (int d0 = 0; d0 < DDIM; d0 += DCH) {
        __syncthreads();
#pragma unroll
        for (int i = 0; i < 8; ++i) {
            int r = w * 8 + i;                                   // wave-uniform
            load_lds16(eqT + (size_t)(d0 + r) * NROWS + n0 + lane * 4,
                       &ks[r * 256]);
        }
        {
            int mmq = t >> 5, dd = t & 31;
            es[t] = ek[(size_t)(m0 + mmq) * DDIM + d0 + dd];
        }
        if (t < DCH) wws[t] = Ww[d0 + t];
        __syncthreads();

#pragma unroll
        for (int dd = 0; dd < DCH; ++dd) {
            float4 kv = *(const float4*)&ks[dd * 256 + lane * 4];
            float wv  = wws[dd];
            v2f w2 = {wv, wv};
#pragma unroll
            for (int mm = 0; mm < 2; ++mm) {
                float ekv = es[(w * 2 + mm) * DCH + dd];
                v2f e2 = {ekv, ekv};
                v2f t01 = __builtin_elementwise_fma(e2, (v2f){kv.x, kv.y}, one2);
                v2f t23 = __builtin_elementwise_fma(e2, (v2f){kv.z, kv.w}, one2);
                v2f r01 = {__builtin_amdgcn_rcpf(t01.x), __builtin_amdgcn_rcpf(t01.y)};
                v2f r23 = {__builtin_amdgcn_rcpf(t23.x), __builtin_amdgcn_rcpf(t23.y)};
                acc01[mm] = __builtin_elementwise_fma(w2, r01, acc01[mm]);
                acc23[mm] = __builtin_elementwise_fma(w2, r23, acc23[mm]);
            }
        }
    }

    const float C2 = -2.8853900817779268f;   // -2*log2(e)
    const int nb = n0 + lane * 4;
#pragma unroll
    for (int mm = 0; mm < 2; ++mm) {
        int m = m0 + w * 2 + mm;
        int mk0 = mask[(size_t)(nb + 0) * MDIM + m];
        int mk1 = mask[(size_t)(nb + 1) * MDIM + m];
        int mk2 = mask[(size_t)(nb + 2) * MDIM + m];
        int mk3 = mask[(size_t)(nb + 3) * MDIM + m];
        float4 o;
        o.x = mk0 ? __builtin_amdgcn_exp2f(acc01[mm].x * C2) : 0.f;
        o.y = mk1 ? __builtin_amdgcn_exp2f(acc01[mm].y * C2) : 0.f;
        o.z = mk2 ? __builtin_amdgcn_exp2f(acc23[mm].x * C2) : 0.f;
        o.w = mk3 ? __builtin_amdgcn_exp2f(acc23[mm].y * C2) : 0.f;
        *(float4*)&PT[(size_t)m * NROWS + nb] = o;
    }
}

// ---------------- Row-sum inverse: rinv[n] = 1 / sum_m PT[m][n] -------------
__global__ __launch_bounds__(256) void rsum_kernel(const float* __restrict__ PT,
                                                   float* __restrict__ rinv)
{
    __shared__ float red[4][64];
    const int t = threadIdx.x, lane = t & 63, w = t >> 6;
    const int n = blockIdx.x * 64 + lane;
    float s = 0.f;
#pragma unroll 8
    for (int m = w * 256; m < w * 256 + 256; ++m)
        s += PT[(size_t)m * NROWS + n];
    red[w][lane] = s;
    __syncthreads();
    if (t < 64) {
        float tot = (red[0][t] + red[1][t]) + (red[2][t] + red[3][t]);
        rinv[blockIdx.x * 64 + t] = __builtin_amdgcn_rcpf(tot);
    }
}

// ---------------- Context GEMM: out[n][d] = (sum_m PT[m][n]*vp[m][d])*rinv[n]
// 64(n) x 32(d) tile -> grid 256. Both tiles m-major natural copies.
__global__ __launch_bounds__(256) void ctx_gemm(const float* __restrict__ PT,
                                                const float* __restrict__ vp,
                                                const float* __restrict__ rinv,
                                                float* __restrict__ out)
{
    __shared__ __align__(16) float pts[64 * 68];   // [m][n], stride 68
    __shared__ __align__(16) float vs[64 * 36];    // [m][d], stride 36
    const int t  = threadIdx.x;
    const int tx = t & 15;      // d-frag (2 d)
    const int ty = t >> 4;      // n-frag (4 n)
    const int n0 = blockIdx.y * 64;
    const int d0 = blockIdx.x * 32;

    float acc[4][2] = {};

    for (int m0 = 0; m0 < MDIM; m0 += 64) {
        __syncthreads();
#pragma unroll
        for (int p = 0; p < 4; ++p) {
            int idx = t + p * 256;
            int r = idx >> 4, c4 = idx & 15;
            *(float4*)&pts[r * 68 + c4 * 4] =
                *(const float4*)&PT[(size_t)(m0 + r) * NROWS + n0 + c4 * 4];
        }
#pragma unroll
        for (int p = 0; p < 2; ++p) {
            int idx = t + p * 256;
            int r = idx >> 3, c4 = idx & 7;
            *(float4*)&vs[r * 36 + c4 * 4] =
                *(const float4*)&vp[(size_t)(m0 + r) * DDIM + d0 + c4 * 4];
        }
        __syncthreads();
#pragma unroll 8
        for (int m = 0; m < 64; ++m) {
            float4 a = *(const float4*)&pts[m * 68 + ty * 4];   // broadcast
            float2 b = *(const float2*)&vs[m * 36 + tx * 2];    // conflict-free
            float av4[4] = {a.x, a.y, a.z, a.w};
#pragma unroll
            for (int i = 0; i < 4; ++i) {
                acc[i][0] = fmaf(av4[i], b.x, acc[i][0]);
                acc[i][1] = fmaf(av4[i], b.y, acc[i][1]);
            }
        }
    }

#pragma unroll
    for (int i = 0; i < 4; ++i) {
        int n = n0 + ty * 4 + i;
        float inv = rinv[n];
        float2 o = {acc[i][0] * inv, acc[i][1] * inv};
        *(float2*)&out[(size_t)n * DDIM + d0 + tx * 2] = o;
    }
}

extern "C" void kernel_launch(void* const* d_in, const int* in_sizes, int n_in,
                              void* d_out, int out_size, void* d_ws, size_t ws_size,
                              hipStream_t stream)
{
    const float* q    = (const float*)d_in[0];
    const float* k    = (const float*)d_in[1];
    const float* v    = (const float*)d_in[2];
    const int*   mask = (const int*)d_in[3];
    const float* Wq   = (const float*)d_in[4];
    const float* bq   = (const float*)d_in[5];
    const float* Wk   = (const float*)d_in[6];
    const float* bk   = (const float*)d_in[7];
    const float* Wv   = (const float*)d_in[8];
    const float* bv   = (const float*)d_in[9];
    const float* Ww   = (const float*)d_in[10];
    // d_in[11] (bw) cancels under softmax.

    float* ws   = (float*)d_ws;
    float* eqT  = ws;                        // 512K floats [512 d][1024 n]
    float* ek   = ws + 524288;               // 512K [1024 m][512 d]
    float* vp   = ws + 1048576;              // 512K [1024 m][512 d]
    float* PT   = ws + 1572864;              // 1M  [1024 m][1024 n]
    float* rinv = ws;                        // 1K, reuses eqT (dead after score)
    float* out  = (float*)d_out;

    const float CS = 2.8853900817779268f;    // 2*log2(e)

    dim3 b256(256);
    proj_gemm<<<dim3(16, 16, 3), b256, 0, stream>>>(q, k, v, Wq, bq, Wk, bk,
                                                    Wv, bv, eqT, ek, vp, CS);
    score_kernel<<<dim3(4, 128), b256, 0, stream>>>(eqT, ek, Ww, mask, PT);
    rsum_kernel<<<dim3(16), b256, 0, stream>>>(PT, rinv);
    ctx_gemm<<<dim3(16, 16), b256, 0, stream>>>(PT, vp, rinv, out);
}

// Round 6
// 230.470 us; speedup vs baseline: 1.0980x; 1.0980x over previous
//
#include <hip/hip_runtime.h>
#include <hip/hip_bf16.h>
#include <float.h>

// N=1024, M=1024, D=512, fp32.
// tanh(q+k) = 1 - 2/(1+exp2(CS*(q+k))), CS=2*log2(e), exp2 factorized:
// eqT[d][n]=min(exp2(CS*qp),2^13)^T, ek[m][d]=min(exp2(CS*kp),2^13).
// Score s[n,m] = -2*sum_d Ww[d]/(1+eq*ek) (row-const dropped; softmax
// shift-invariant). |s|<=2*sum|Ww|~36 -> exp never overflows -> NO max pass.
// Quad-rational trick: w0/A0+w1/A1+w2/A2+w3/A3 merged to ONE rcp (v_rcp_f32
// is 1/8-rate: 16cyc/wave -- measured via R3/R4/R5 fit). Clamp 2^13 bounds
// den <= 2^108 < fp32 max.
// Score writes PT[m][n] = mask ? exp(s) : 0 (coalesced). ctx folds the
// row-sum into its staging loop and normalizes in the epilogue: 3 kernels.
// ws (floats): eqT[512K] ek[512K] vp[512K] PT[1M] = 10.5 MB.

#define NROWS 1024
#define DDIM  512
#define MDIM  1024

__device__ __forceinline__ void load_lds16(const float* g, float* l) {
    __builtin_amdgcn_global_load_lds(
        (const __attribute__((address_space(1))) void*)g,
        (__attribute__((address_space(3))) void*)l, 16, 0, 0);
}

// ---------------- Fused projection GEMMs (A^T-B form) ------------------------
// out[R][C] = sum_k A[r][k]*B[c][k] (+bias, optional clamp(exp2*CS)).
// z=0: eqT[d][n]: A=Wq, B=q,  bias on R-row (d), exp2.  R=512,  C=1024
// z=1: ek[m][d]:  A=k,  B=Wk, bias on C-col (d), exp2.  R=1024, C=512
// z=2: vp[m][d]:  A=v,  B=Wv, bias on C-col (d).        R=1024, C=512
// LDS k-major with 16B-block XOR swizzle: coalesced global reads,
// conflict-free transposed stores AND b128 fragment reads.
__global__ __launch_bounds__(256) void proj_gemm(
    const float* __restrict__ q, const float* __restrict__ kk_,
    const float* __restrict__ v,
    const float* __restrict__ Wq, const float* __restrict__ bq,
    const float* __restrict__ Wk, const float* __restrict__ bk,
    const float* __restrict__ Wv, const float* __restrict__ bv,
    float* __restrict__ eqT, float* __restrict__ ek, float* __restrict__ vp,
    float CS)
{
    __shared__ __align__(16) float As[64 * 64];
    __shared__ __align__(16) float Bs[64 * 64];

    const float* A; const float* B; const float* bias; float* out;
    int C, expo, biasRow;
    if (blockIdx.z == 0)      { A = Wq;  B = q;  bias = bq; out = eqT; C = 1024; expo = 1; biasRow = 1; }
    else if (blockIdx.z == 1) { A = kk_; B = Wk; bias = bk; out = ek;  C = 512;  expo = 1; biasRow = 0; }
    else                      { A = v;   B = Wv; bias = bv; out = vp;  C = 512;  expo = 0; biasRow = 0; }

    // grid (16, 8, 3): z=0 has R=512 (8 tiles) x C=1024 (16); z=1,2 reversed.
    const int bi = (blockIdx.z == 0) ? blockIdx.y : blockIdx.x;   // R tile
    const int bj = (blockIdx.z == 0) ? blockIdx.x : blockIdx.y;   // C tile

    const int t  = threadIdx.x;
    const int tx = t & 15;
    const int ty = t >> 4;
    const int i0 = bi * 64;
    const int j0 = bj * 64;

    float acc[4][4] = {};

    for (int k0 = 0; k0 < DDIM; k0 += 64) {
        __syncthreads();
#pragma unroll
        for (int p = 0; p < 4; ++p) {
            int idx = t + p * 256;
            int r = idx >> 4, c4 = idx & 15;          // lanes sweep k: coalesced
            float4 av = *(const float4*)&A[(size_t)(i0 + r) * DDIM + k0 + c4 * 4];
            float4 bf = *(const float4*)&B[(size_t)(j0 + r) * DDIM + k0 + c4 * 4];
            int base = (c4 * 4) * 64 + (((r >> 2) ^ c4) << 2) + (r & 3);
            As[base]       = av.x;  As[base + 64]  = av.y;
            As[base + 128] = av.z;  As[base + 192] = av.w;
            Bs[base]       = bf.x;  Bs[base + 64]  = bf.y;
            Bs[base + 128] = bf.z;  Bs[base + 192] = bf.w;
        }
        __syncthreads();
#pragma unroll
        for (int kg = 0; kg < 16; ++kg) {
            const int ao = ((ty ^ kg) << 2);
            const int bo = ((tx ^ kg) << 2);
#pragma unroll
            for (int kq = 0; kq < 4; ++kq) {
                int kk = kg * 4 + kq;
                float4 a = *(const float4*)&As[kk * 64 + ao];
                float4 b = *(const float4*)&Bs[kk * 64 + bo];
                float av4[4] = {a.x, a.y, a.z, a.w};
                float bv4[4] = {b.x, b.y, b.z, b.w};
#pragma unroll
                for (int i = 0; i < 4; ++i)
#pragma unroll
                    for (int j = 0; j < 4; ++j)
                        acc[i][j] = fmaf(av4[i], bv4[j], acc[i][j]);
            }
        }
    }

    const float CLAMP = 8192.0f;   // 2^13: bounds quad-rational den < 2^127
#pragma unroll
    for (int i = 0; i < 4; ++i) {
        int row = i0 + ty * 4 + i;
        float4 o;
        float ov[4];
#pragma unroll
        for (int j = 0; j < 4; ++j) {
            float bval = biasRow ? bias[row] : bias[j0 + tx * 4 + j];
            float val = acc[i][j] + bval;
            ov[j] = expo ? fminf(__builtin_amdgcn_exp2f(val * CS), CLAMP) : val;
        }
        o.x = ov[0]; o.y = ov[1]; o.z = ov[2]; o.w = ov[3];
        *(float4*)&out[(size_t)row * C + j0 + tx * 4] = o;
    }
}

// ---------------- Score kernel ----------------------------------------------
// PT[m][n] = mask[n][m] ? exp(-2*sum_d Ww[d]/(1+eqT[d][n]*ek[m][d])) : 0
// Block: 4 waves; wave w owns ONE m; lane owns 4 n. Grid (4 n-chunks, 256
// m-chunks) = 1024 blocks = 4/CU. ek row + Ww via wave-uniform s_loads.
// Quad-rational: 4 d-terms share one rcp (14 VALU + 1 rcp per 4 elems).
#define DCH 32
__global__ __launch_bounds__(256) void score_kernel(const float* __restrict__ eqT,
                                                    const float* __restrict__ ek,
                                                    const float* __restrict__ Ww,
                                                    const int* __restrict__ mask,
                                                    float* __restrict__ PT)
{
    __shared__ __align__(16) float ks[DCH * 256];   // 32 KB
    const int t    = threadIdx.x;
    const int lane = t & 63;
    const int w    = t >> 6;
    const int n0   = blockIdx.x * 256;
    const int m    = blockIdx.y * 4 + w;
    const int mu   = __builtin_amdgcn_readfirstlane(m);
    const float* __restrict__ ekrow = ek + (size_t)mu * DDIM;

    float acc[4] = {};

    for (int d0 = 0; d0 < DDIM; d0 += DCH) {
        __syncthreads();
#pragma unroll
        for (int i = 0; i < 8; ++i) {
            int r = w * 8 + i;                                   // wave-uniform
            load_lds16(eqT + (size_t)(d0 + r) * NROWS + n0 + lane * 4,
                       &ks[r * 256]);
        }
        __syncthreads();   // drains vmcnt -> global_load_lds data visible

#pragma unroll
        for (int dq = 0; dq < DCH; dq += 4) {
            float e0 = ekrow[d0 + dq + 0], e1 = ekrow[d0 + dq + 1];
            float e2 = ekrow[d0 + dq + 2], e3 = ekrow[d0 + dq + 3];
            float w0 = Ww[d0 + dq + 0], w1 = Ww[d0 + dq + 1];
            float w2 = Ww[d0 + dq + 2], w3 = Ww[d0 + dq + 3];
            float4 k0 = *(const float4*)&ks[(dq + 0) * 256 + lane * 4];
            float4 k1 = *(const float4*)&ks[(dq + 1) * 256 + lane * 4];
            float4 k2 = *(const float4*)&ks[(dq + 2) * 256 + lane * 4];
            float4 k3 = *(const float4*)&ks[(dq + 3) * 256 + lane * 4];
            float kv0[4] = {k0.x, k0.y, k0.z, k0.w};
            float kv1[4] = {k1.x, k1.y, k1.z, k1.w};
            float kv2[4] = {k2.x, k2.y, k2.z, k2.w};
            float kv3[4] = {k3.x, k3.y, k3.z, k3.w};
#pragma unroll
            for (int j = 0; j < 4; ++j) {
                float A0 = fmaf(kv0[j], e0, 1.0f);
                float A1 = fmaf(kv1[j], e1, 1.0f);
                float A2 = fmaf(kv2[j], e2, 1.0f);
                float A3 = fmaf(kv3[j], e3, 1.0f);
                float n01 = fmaf(w1, A0, w0 * A1);
                float d01 = A0 * A1;
                float n23 = fmaf(w3, A2, w2 * A3);
                float d23 = A2 * A3;
                float num = fmaf(n01, d23, n23 * d01);
                float den = d01 * d23;
                acc[j] = fmaf(num, __builtin_amdgcn_rcpf(den), acc[j]);
            }
        }
    }

    const float C2 = -2.8853900817779268f;   // -2*log2(e)
    const int nb = n0 + lane * 4;
    float4 o;
    float ov[4];
#pragma unroll
    for (int j = 0; j < 4; ++j) {
        int mk = mask[(size_t)(nb + j) * MDIM + m];
        ov[j] = mk ? __builtin_amdgcn_exp2f(acc[j] * C2) : 0.f;
    }
    o.x = ov[0]; o.y = ov[1]; o.z = ov[2]; o.w = ov[3];
    *(float4*)&PT[(size_t)m * NROWS + nb] = o;
}

// ---------------- Context GEMM + folded rowsum + normalize -------------------
// out[n][d] = (sum_m PT[m][n]*vp[m][d]) / (sum_m PT[m][n])
// 64(n) x 32(d) tile, grid (16,16)=256 blocks, full m per block -> each block
// computes its n-range rowsums during staging (redundant across d-tiles, free).
__global__ __launch_bounds__(256) void ctx_gemm(const float* __restrict__ PT,
                                                const float* __restrict__ vp,
                                                float* __restrict__ out)
{
    __shared__ __align__(16) float pts[64 * 68];   // [m][n], stride 68
    __shared__ __align__(16) float vs[64 * 36];    // [m][d], stride 36
    __shared__ float rinvs[64];
    const int t  = threadIdx.x;
    const int tx = t & 15;      // d-frag (2 d)
    const int ty = t >> 4;      // n-frag (4 n)
    const int n0 = blockIdx.y * 64;
    const int d0 = blockIdx.x * 32;

    float acc[4][2] = {};
    float psum[4] = {};          // partial rowsums for n = n0+(t&15)*4+j

    for (int m0 = 0; m0 < MDIM; m0 += 64) {
        __syncthreads();
#pragma unroll
        for (int p = 0; p < 4; ++p) {
            int idx = t + p * 256;
            int r = idx >> 4, c4 = idx & 15;       // c4 == t&15 for all p
            float4 pf = *(const float4*)&PT[(size_t)(m0 + r) * NROWS + n0 + c4 * 4];
            *(float4*)&pts[r * 68 + c4 * 4] = pf;
            psum[0] += pf.x; psum[1] += pf.y; psum[2] += pf.z; psum[3] += pf.w;
        }
#pragma unroll
        for (int p = 0; p < 2; ++p) {
            int idx = t + p * 256;
            int r = idx >> 3, c4 = idx & 7;
            *(float4*)&vs[r * 36 + c4 * 4] =
                *(const float4*)&vp[(size_t)(m0 + r) * DDIM + d0 + c4 * 4];
        }
        __syncthreads();
#pragma unroll 8
        for (int mm = 0; mm < 64; ++mm) {
            float4 a = *(const float4*)&pts[mm * 68 + ty * 4];   // broadcast
            float2 b = *(const float2*)&vs[mm * 36 + tx * 2];    // conflict-free
            float av4[4] = {a.x, a.y, a.z, a.w};
#pragma unroll
            for (int i = 0; i < 4; ++i) {
                acc[i][0] = fmaf(av4[i], b.x, acc[i][0]);
                acc[i][1] = fmaf(av4[i], b.y, acc[i][1]);
            }
        }
    }

    // reduce psum (16 threads per n-quad) -> rinvs[64]
    __syncthreads();
    float4 ps = {psum[0], psum[1], psum[2], psum[3]};
    *(float4*)&pts[t * 4] = ps;                    // repurpose pts
    __syncthreads();
    if (t < 64) {
        float tot = 0.f;
#pragma unroll
        for (int g = 0; g < 16; ++g) tot += pts[g * 64 + t];   // consecutive: bank-free
        rinvs[t] = __builtin_amdgcn_rcpf(tot);
    }
    __syncthreads();

#pragma unroll
    for (int i = 0; i < 4; ++i) {
        int n = n0 + ty * 4 + i;
        float inv = rinvs[ty * 4 + i];
        float2 o = {acc[i][0] * inv, acc[i][1] * inv};
        *(float2*)&out[(size_t)n * DDIM + d0 + tx * 2] = o;
    }
}

extern "C" void kernel_launch(void* const* d_in, const int* in_sizes, int n_in,
                              void* d_out, int out_size, void* d_ws, size_t ws_size,
                              hipStream_t stream)
{
    const float* q    = (const float*)d_in[0];
    const float* k    = (const float*)d_in[1];
    const float* v    = (const float*)d_in[2];
    const int*   mask = (const int*)d_in[3];
    const float* Wq   = (const float*)d_in[4];
    const float* bq   = (const float*)d_in[5];
    const float* Wk   = (const float*)d_in[6];
    const float* bk   = (const float*)d_in[7];
    const float* Wv   = (const float*)d_in[8];
    const float* bv   = (const float*)d_in[9];
    const float* Ww   = (const float*)d_in[10];
    // d_in[11] (bw) cancels under softmax.

    float* ws  = (float*)d_ws;
    float* eqT = ws;                         // 512K floats [512 d][1024 n]
    float* ek  = ws + 524288;                // 512K [1024 m][512 d]
    float* vp  = ws + 1048576;               // 512K [1024 m][512 d]
    float* PT  = ws + 1572864;               // 1M  [1024 m][1024 n]
    float* out = (float*)d_out;

    const float CS = 2.8853900817779268f;    // 2*log2(e)

    dim3 b256(256);
    proj_gemm<<<dim3(16, 8, 3), b256, 0, stream>>>(q, k, v, Wq, bq, Wk, bk,
                                                   Wv, bv, eqT, ek, vp, CS);
    score_kernel<<<dim3(4, 256), b256, 0, stream>>>(eqT, ek, Ww, mask, PT);
    ctx_gemm<<<dim3(16, 16), b256, 0, stream>>>(PT, vp, out);
}